// Round 1
// baseline (411.149 us; speedup 1.0000x reference)
//
#include <hip/hip_runtime.h>
#include <math.h>

#define SEQ 4096
#define DIM 1024
#define HEADS 8
#define DINNER 512
#define QKVW 1536
#define PAD 80   // LDS row stride in bf16 elems: 160B = 10 x 16B granules, balanced banks
#define CHUNK 16 // K-tiles (of 64) per split-KV chunk

typedef unsigned short u16;
typedef __attribute__((ext_vector_type(8))) short s8v;   // 8 bf16 (4 VGPRs)
typedef __attribute__((ext_vector_type(4))) float f4v;   // 4 fp32 acc
#define MFMA(a, b, c) __builtin_amdgcn_mfma_f32_16x16x32_bf16(a, b, c, 0, 0, 0)

__device__ __forceinline__ u16 f2bf(float f) {
    unsigned u = __float_as_uint(f);
    u += 0x7fff + ((u >> 16) & 1);   // RNE
    return (u16)(u >> 16);
}
__device__ __forceinline__ float bf2f(u16 b) { return __uint_as_float(((unsigned)b) << 16); }

// ---------- RMSNorm -> split bf16 (hi, lo) ----------
__global__ __launch_bounds__(256) void rmsnorm_split(const float* __restrict__ x,
                                                     const float* __restrict__ gamma,
                                                     u16* __restrict__ hi,
                                                     u16* __restrict__ lo) {
    __shared__ float red[4];
    const int row = blockIdx.x, t = threadIdx.x;
    const float* xr = x + (size_t)row * DIM;
    float v[4];
    float ss = 0.f;
#pragma unroll
    for (int i = 0; i < 4; ++i) { v[i] = xr[t + i * 256]; ss += v[i] * v[i]; }
#pragma unroll
    for (int off = 32; off >= 1; off >>= 1) ss += __shfl_xor(ss, off, 64);
    if ((t & 63) == 0) red[t >> 6] = ss;
    __syncthreads();
    float scale = 32.0f / fmaxf(sqrtf(red[0] + red[1] + red[2] + red[3]), 1e-12f);
#pragma unroll
    for (int i = 0; i < 4; ++i) {
        int c = t + i * 256;
        float y = v[i] * scale * gamma[c];
        u16 h = f2bf(y);
        hi[(size_t)row * DIM + c] = h;
        lo[(size_t)row * DIM + c] = f2bf(y - bf2f(h));
    }
}

// ---------- transpose fp32 [R][C] -> bf16 hi/lo [C][R] ----------
__global__ __launch_bounds__(256) void transpose_split(const float* __restrict__ in,
                                                       u16* __restrict__ hi,
                                                       u16* __restrict__ lo,
                                                       int R, int C, int want_lo) {
    __shared__ float tile[64][65];
    const int c0 = blockIdx.x * 64, r0 = blockIdx.y * 64;
    const int t = threadIdx.x, col = t & 63, rb = t >> 6;
#pragma unroll
    for (int j = 0; j < 16; ++j)
        tile[rb + j * 4][col] = in[(size_t)(r0 + rb + j * 4) * C + c0 + col];
    __syncthreads();
#pragma unroll
    for (int j = 0; j < 16; ++j) {
        int cc = rb + j * 4;
        float v = tile[col][cc];
        size_t oi = (size_t)(c0 + cc) * R + r0 + col;
        u16 h = f2bf(v);
        hi[oi] = h;
        if (want_lo) lo[oi] = f2bf(v - bf2f(h));
    }
}

// ---------- QKV GEMM, split-bf16 (3 MFMAs), fused split/scale epilogue ----------
__global__ __launch_bounds__(256) void gemm_qkv_split(
    const u16* __restrict__ Ah, const u16* __restrict__ Al,
    const u16* __restrict__ Bh, const u16* __restrict__ Bl,
    u16* __restrict__ qh, u16* __restrict__ ql,
    u16* __restrict__ kh, u16* __restrict__ kl, u16* __restrict__ vtp) {
    __shared__ u16 Ash[64 * PAD], Asl[64 * PAD], Bsh[64 * PAD], Bsl[64 * PAD];
    const int t = threadIdx.x;
    const int bn = blockIdx.x * 64, bm = blockIdx.y * 64;
    const int w = t >> 6, lane = t & 63, m = lane & 15, q = lane >> 4;
    f4v acc[4] = {{0.f, 0.f, 0.f, 0.f}, {0.f, 0.f, 0.f, 0.f},
                  {0.f, 0.f, 0.f, 0.f}, {0.f, 0.f, 0.f, 0.f}};
    for (int k0 = 0; k0 < DIM; k0 += 64) {
        __syncthreads();
#pragma unroll
        for (int i = 0; i < 2; ++i) {
            int c = t + i * 256, row = c >> 3, ch = (c & 7) * 8;
            *(uint4*)&Ash[row * PAD + ch] = *(const uint4*)&Ah[(size_t)(bm + row) * DIM + k0 + ch];
            *(uint4*)&Asl[row * PAD + ch] = *(const uint4*)&Al[(size_t)(bm + row) * DIM + k0 + ch];
            *(uint4*)&Bsh[row * PAD + ch] = *(const uint4*)&Bh[(size_t)(bn + row) * DIM + k0 + ch];
            *(uint4*)&Bsl[row * PAD + ch] = *(const uint4*)&Bl[(size_t)(bn + row) * DIM + k0 + ch];
        }
        __syncthreads();
#pragma unroll
        for (int kk = 0; kk < 64; kk += 32) {
            s8v ah = *(const s8v*)&Ash[(w * 16 + m) * PAD + kk + q * 8];
            s8v al = *(const s8v*)&Asl[(w * 16 + m) * PAD + kk + q * 8];
#pragma unroll
            for (int ct = 0; ct < 4; ++ct) {
                s8v bh = *(const s8v*)&Bsh[(ct * 16 + m) * PAD + kk + q * 8];
                s8v bl = *(const s8v*)&Bsl[(ct * 16 + m) * PAD + kk + q * 8];
                acc[ct] = MFMA(ah, bh, acc[ct]);
                acc[ct] = MFMA(al, bh, acc[ct]);
                acc[ct] = MFMA(ah, bl, acc[ct]);
            }
        }
    }
    const int region = bn >> 9;   // uniform per block
#pragma unroll
    for (int ct = 0; ct < 4; ++ct) {
#pragma unroll
        for (int r = 0; r < 4; ++r) {
            int gr = bm + w * 16 + q * 4 + r;
            int gc = bn + ct * 16 + m;
            float v = acc[ct][r];
            if (region == 0) {
                v *= 8.0f;   // q * sqrt(d), faithful to reference
                u16 h = f2bf(v);
                qh[(size_t)gr * DINNER + gc] = h;
                ql[(size_t)gr * DINNER + gc] = f2bf(v - bf2f(h));
            } else if (region == 1) {
                u16 h = f2bf(v);
                kh[(size_t)gr * DINNER + (gc - 512)] = h;
                kl[(size_t)gr * DINNER + (gc - 512)] = f2bf(v - bf2f(h));
            } else {
                vtp[(size_t)(gc - 1024) * SEQ + gr] = f2bf(v);
            }
        }
    }
}

// ---------- split-KV flash attention chunk kernel ----------
// blockIdx.x encodes (qt descending, chunk c in 0..3); qt handles K-tiles [c*16, min(qt, c*16+15)].
// Q hi/lo fragments live in registers (each wave reads only its own 16 rows).
// K/V tiles are register-prefetched one iteration ahead (global latency hides under compute).
// Writes RAW partial o (fp32), plus per-row running (m, l) for the merge pass.
__global__ __launch_bounds__(256, 4) void attn_chunk(
    const u16* __restrict__ qhp, const u16* __restrict__ qlp,
    const u16* __restrict__ kh, const u16* __restrict__ kl,
    const u16* __restrict__ vt,
    float* __restrict__ po0, float* __restrict__ po1,
    float* __restrict__ po2, float* __restrict__ po3,
    float* __restrict__ ml) {
    __shared__ u16 KP[64 * PAD], Kl[64 * PAD], Vt[64 * PAD];
    const int t = threadIdx.x;
    const int bx = blockIdx.x;
    const int qt = 63 - (bx >> 2), c = bx & 3, h = blockIdx.y;
    if (c * CHUNK > qt) return;
    const int kt0 = c * CHUNK;
    const int kt1 = (qt < kt0 + CHUNK - 1) ? qt : (kt0 + CHUNK - 1);
    const int w = t >> 6, lane = t & 63, m = lane & 15, q = lane >> 4;

    // Q fragments in registers: row = qt*64 + w*16 + m, cols q*8 + {0..7} and 32 + q*8 + {0..7}
    const size_t qrow = (size_t)(qt * 64 + w * 16 + m) * DINNER + h * 64;
    const s8v qf_h0 = *(const s8v*)&qhp[qrow + q * 8];
    const s8v qf_h1 = *(const s8v*)&qhp[qrow + 32 + q * 8];
    const s8v qf_l0 = *(const s8v*)&qlp[qrow + q * 8];
    const s8v qf_l1 = *(const s8v*)&qlp[qrow + 32 + q * 8];

    f4v o[4] = {{0.f, 0.f, 0.f, 0.f}, {0.f, 0.f, 0.f, 0.f},
                {0.f, 0.f, 0.f, 0.f}, {0.f, 0.f, 0.f, 0.f}};
    float mi[4] = {-1e30f, -1e30f, -1e30f, -1e30f};
    float li[4] = {0.f, 0.f, 0.f, 0.f};

    // prologue: prefetch first K/V tile into registers
    uint4 rk[2], rl[2], rv[2];
#pragma unroll
    for (int i = 0; i < 2; ++i) {
        int c2 = t + i * 256, row = c2 >> 3, ch = (c2 & 7) * 8;
        rk[i] = *(const uint4*)&kh[(size_t)(kt0 * 64 + row) * DINNER + h * 64 + ch];
        rl[i] = *(const uint4*)&kl[(size_t)(kt0 * 64 + row) * DINNER + h * 64 + ch];
        rv[i] = *(const uint4*)&vt[(size_t)(h * 64 + row) * SEQ + kt0 * 64 + ch];
    }

    for (int kt = kt0; kt <= kt1; ++kt) {
        __syncthreads();   // prior iteration's P/Vt consumers done
#pragma unroll
        for (int i = 0; i < 2; ++i) {
            int c2 = t + i * 256, row = c2 >> 3, ch = (c2 & 7) * 8;
            *(uint4*)&KP[row * PAD + ch] = rk[i];
            *(uint4*)&Kl[row * PAD + ch] = rl[i];
            *(uint4*)&Vt[row * PAD + ch] = rv[i];
        }
        if (kt < kt1) {   // prefetch next tile; latency hides under QK/softmax/PV
#pragma unroll
            for (int i = 0; i < 2; ++i) {
                int c2 = t + i * 256, row = c2 >> 3, ch = (c2 & 7) * 8;
                rk[i] = *(const uint4*)&kh[(size_t)((kt + 1) * 64 + row) * DINNER + h * 64 + ch];
                rl[i] = *(const uint4*)&kl[(size_t)((kt + 1) * 64 + row) * DINNER + h * 64 + ch];
                rv[i] = *(const uint4*)&vt[(size_t)(h * 64 + row) * SEQ + (kt + 1) * 64 + ch];
            }
        }
        __syncthreads();

        // S strip (16 rows x 64 cols) per wave, split QK^T: 3 MFMAs per 16x16x32
        f4v s[4] = {{0.f, 0.f, 0.f, 0.f}, {0.f, 0.f, 0.f, 0.f},
                    {0.f, 0.f, 0.f, 0.f}, {0.f, 0.f, 0.f, 0.f}};
#pragma unroll
        for (int ct = 0; ct < 4; ++ct) {
            s8v bh0 = *(const s8v*)&KP[(ct * 16 + m) * PAD + q * 8];
            s8v bl0 = *(const s8v*)&Kl[(ct * 16 + m) * PAD + q * 8];
            s[ct] = MFMA(qf_h0, bh0, s[ct]);
            s[ct] = MFMA(qf_l0, bh0, s[ct]);
            s[ct] = MFMA(qf_h0, bl0, s[ct]);
            s8v bh1 = *(const s8v*)&KP[(ct * 16 + m) * PAD + 32 + q * 8];
            s8v bl1 = *(const s8v*)&Kl[(ct * 16 + m) * PAD + 32 + q * 8];
            s[ct] = MFMA(qf_h1, bh1, s[ct]);
            s[ct] = MFMA(qf_l1, bh1, s[ct]);
            s[ct] = MFMA(qf_h1, bl1, s[ct]);
        }
        if (kt == qt) {   // causal: mask col > row (tile-local, same tile offset)
#pragma unroll
            for (int ct = 0; ct < 4; ++ct)
#pragma unroll
                for (int r = 0; r < 4; ++r)
                    if (ct * 16 + m > w * 16 + q * 4 + r) s[ct][r] = -1e30f;
        }

        // online softmax: row = w*16 + q*4 + r lives on the 16-lane group (lane>>4)==q
        float alpha[4];
#pragma unroll
        for (int r = 0; r < 4; ++r) {
            float rm = fmaxf(fmaxf(s[0][r], s[1][r]), fmaxf(s[2][r], s[3][r]));
#pragma unroll
            for (int off = 8; off >= 1; off >>= 1) rm = fmaxf(rm, __shfl_xor(rm, off, 64));
            float mn = fmaxf(mi[r], rm);
            alpha[r] = __expf(mi[r] - mn);
            mi[r] = mn;
            float rs = 0.f;
#pragma unroll
            for (int ct = 0; ct < 4; ++ct) {
                s[ct][r] = __expf(s[ct][r] - mn);
                rs += s[ct][r];
            }
#pragma unroll
            for (int off = 8; off >= 1; off >>= 1) rs += __shfl_xor(rs, off, 64);
            li[r] = li[r] * alpha[r] + rs;
        }

        __syncthreads();   // all waves done reading KP as K-hi before P overwrite
#pragma unroll
        for (int ct = 0; ct < 4; ++ct)
#pragma unroll
            for (int r = 0; r < 4; ++r) {
                KP[(w * 16 + q * 4 + r) * PAD + ct * 16 + m] = f2bf(s[ct][r]);
                o[ct][r] *= alpha[r];
            }
        // PV: each wave reads only its own P rows (w*16..w*16+15) -> no barrier needed
#pragma unroll
        for (int kk = 0; kk < 64; kk += 32) {
            s8v ap = *(const s8v*)&KP[(w * 16 + m) * PAD + kk + q * 8];
#pragma unroll
            for (int ct = 0; ct < 4; ++ct) {
                s8v bv = *(const s8v*)&Vt[(ct * 16 + m) * PAD + kk + q * 8];
                o[ct] = MFMA(ap, bv, o[ct]);
            }
        }
    }

    // epilogue: raw partial o (fp32) + per-row (m, l)
    float* po = (c == 0) ? po0 : (c == 1) ? po1 : (c == 2) ? po2 : po3;
    const size_t pbase = (size_t)(h * 64 + qt) * 64 * 64;
#pragma unroll
    for (int ct = 0; ct < 4; ++ct)
#pragma unroll
        for (int r = 0; r < 4; ++r)
            po[pbase + (size_t)(w * 16 + q * 4 + r) * 64 + ct * 16 + m] = o[ct][r];
    if (m == 0) {
#pragma unroll
        for (int r = 0; r < 4; ++r) {
            int row = w * 16 + q * 4 + r;
            ml[((size_t)(h * 64 + qt) * 4 + c) * 128 + row] = mi[r];
            ml[((size_t)(h * 64 + qt) * 4 + c) * 128 + 64 + row] = li[r];
        }
    }
}

// ---------- merge split-KV partials -> atto bf16 ----------
__global__ __launch_bounds__(256) void attn_merge(
    const float* __restrict__ po0, const float* __restrict__ po1,
    const float* __restrict__ po2, const float* __restrict__ po3,
    const float* __restrict__ ml, u16* __restrict__ atto) {
    const int qt = blockIdx.x, h = blockIdx.y;
    const int nc = qt / CHUNK + 1;
    const int t = threadIdx.x, col = t & 63, rg = t >> 6;
    const size_t mlb = (size_t)(h * 64 + qt) * 4;
    const size_t pb = (size_t)(h * 64 + qt) * 64;
    for (int j = 0; j < 16; ++j) {
        int row = rg * 16 + j;
        float mv[4], lv[4];
        float M = -1e30f;
#pragma unroll
        for (int cc = 0; cc < 4; ++cc)
            if (cc < nc) {
                mv[cc] = ml[(mlb + cc) * 128 + row];
                lv[cc] = ml[(mlb + cc) * 128 + 64 + row];
                M = fmaxf(M, mv[cc]);
            }
        const size_t oidx = (pb + row) * 64 + col;
        float acc = 0.f, den = 0.f;
        { float wg = __expf(mv[0] - M); den += lv[0] * wg; acc += wg * po0[oidx]; }
        if (1 < nc) { float wg = __expf(mv[1] - M); den += lv[1] * wg; acc += wg * po1[oidx]; }
        if (2 < nc) { float wg = __expf(mv[2] - M); den += lv[2] * wg; acc += wg * po2[oidx]; }
        if (3 < nc) { float wg = __expf(mv[3] - M); den += lv[3] * wg; acc += wg * po3[oidx]; }
        atto[(size_t)(qt * 64 + row) * DINNER + h * 64 + col] = f2bf(acc / den);
    }
}

// ---------- fallback: original fused flash attention (used if workspace too small) ----------
__global__ __launch_bounds__(256) void attn_mfma(
    const u16* __restrict__ qh, const u16* __restrict__ ql,
    const u16* __restrict__ kh, const u16* __restrict__ kl,
    const u16* __restrict__ vt, u16* __restrict__ atto) {
    __shared__ u16 Qh[64 * PAD], Ql[64 * PAD], KP[64 * PAD], Kl[64 * PAD], Vt[64 * PAD];
    const int t = threadIdx.x;
    const int qt = blockIdx.x, h = blockIdx.y;
    const int w = t >> 6, lane = t & 63, m = lane & 15, q = lane >> 4;

#pragma unroll
    for (int i = 0; i < 2; ++i) {
        int c = t + i * 256, row = c >> 3, ch = (c & 7) * 8;
        *(uint4*)&Qh[row * PAD + ch] =
            *(const uint4*)&qh[(size_t)(qt * 64 + row) * DINNER + h * 64 + ch];
        *(uint4*)&Ql[row * PAD + ch] =
            *(const uint4*)&ql[(size_t)(qt * 64 + row) * DINNER + h * 64 + ch];
    }

    f4v o[4] = {{0.f, 0.f, 0.f, 0.f}, {0.f, 0.f, 0.f, 0.f},
                {0.f, 0.f, 0.f, 0.f}, {0.f, 0.f, 0.f, 0.f}};
    float mi[4] = {-1e30f, -1e30f, -1e30f, -1e30f};
    float li[4] = {0.f, 0.f, 0.f, 0.f};

    for (int kt = 0; kt <= qt; ++kt) {
        __syncthreads();
#pragma unroll
        for (int i = 0; i < 2; ++i) {
            int c = t + i * 256, row = c >> 3, ch = (c & 7) * 8;
            *(uint4*)&KP[row * PAD + ch] =
                *(const uint4*)&kh[(size_t)(kt * 64 + row) * DINNER + h * 64 + ch];
            *(uint4*)&Kl[row * PAD + ch] =
                *(const uint4*)&kl[(size_t)(kt * 64 + row) * DINNER + h * 64 + ch];
            *(uint4*)&Vt[row * PAD + ch] =
                *(const uint4*)&vt[(size_t)(h * 64 + row) * SEQ + kt * 64 + ch];
        }
        __syncthreads();

        f4v s[4] = {{0.f, 0.f, 0.f, 0.f}, {0.f, 0.f, 0.f, 0.f},
                    {0.f, 0.f, 0.f, 0.f}, {0.f, 0.f, 0.f, 0.f}};
#pragma unroll
        for (int kk = 0; kk < 64; kk += 32) {
            s8v ah = *(const s8v*)&Qh[(w * 16 + m) * PAD + kk + q * 8];
            s8v al = *(const s8v*)&Ql[(w * 16 + m) * PAD + kk + q * 8];
#pragma unroll
            for (int ct = 0; ct < 4; ++ct) {
                s8v bh = *(const s8v*)&KP[(ct * 16 + m) * PAD + kk + q * 8];
                s8v bl = *(const s8v*)&Kl[(ct * 16 + m) * PAD + kk + q * 8];
                s[ct] = MFMA(ah, bh, s[ct]);
                s[ct] = MFMA(al, bh, s[ct]);
                s[ct] = MFMA(ah, bl, s[ct]);
            }
        }
        if (kt == qt) {
#pragma unroll
            for (int ct = 0; ct < 4; ++ct)
#pragma unroll
                for (int r = 0; r < 4; ++r)
                    if (ct * 16 + m > w * 16 + q * 4 + r) s[ct][r] = -1e30f;
        }

        float alpha[4];
#pragma unroll
        for (int r = 0; r < 4; ++r) {
            float rm = fmaxf(fmaxf(s[0][r], s[1][r]), fmaxf(s[2][r], s[3][r]));
#pragma unroll
            for (int off = 8; off >= 1; off >>= 1) rm = fmaxf(rm, __shfl_xor(rm, off, 64));
            float mn = fmaxf(mi[r], rm);
            alpha[r] = __expf(mi[r] - mn);
            mi[r] = mn;
            float rs = 0.f;
#pragma unroll
            for (int ct = 0; ct < 4; ++ct) {
                s[ct][r] = __expf(s[ct][r] - mn);
                rs += s[ct][r];
            }
#pragma unroll
            for (int off = 8; off >= 1; off >>= 1) rs += __shfl_xor(rs, off, 64);
            li[r] = li[r] * alpha[r] + rs;
        }

        __syncthreads();
#pragma unroll
        for (int ct = 0; ct < 4; ++ct)
#pragma unroll
            for (int r = 0; r < 4; ++r) {
                KP[(w * 16 + q * 4 + r) * PAD + ct * 16 + m] = f2bf(s[ct][r]);
                o[ct][r] *= alpha[r];
            }
#pragma unroll
        for (int kk = 0; kk < 64; kk += 32) {
            s8v ap = *(const s8v*)&KP[(w * 16 + m) * PAD + kk + q * 8];
#pragma unroll
            for (int ct = 0; ct < 4; ++ct) {
                s8v bv = *(const s8v*)&Vt[(ct * 16 + m) * PAD + kk + q * 8];
                o[ct] = MFMA(ap, bv, o[ct]);
            }
        }
    }

#pragma unroll
    for (int r = 0; r < 4; ++r) {
        float inv = 1.0f / li[r];
#pragma unroll
        for (int ct = 0; ct < 4; ++ct)
            atto[(size_t)(qt * 64 + w * 16 + q * 4 + r) * DINNER + h * 64 + ct * 16 + m] =
                f2bf(o[ct][r] * inv);
    }
}

// ---------- out projection: atto bf16 [4096][512] @ w_out^T bf16 [1024][512] -> fp32 ----------
__global__ __launch_bounds__(256) void gemm_out_bf16(const u16* __restrict__ A,
                                                     const u16* __restrict__ Bt,
                                                     float* __restrict__ C) {
    __shared__ u16 As[64 * PAD], Bs[64 * PAD];
    const int t = threadIdx.x;
    const int bn = blockIdx.x * 64, bm = blockIdx.y * 64;
    const int w = t >> 6, lane = t & 63, m = lane & 15, q = lane >> 4;
    f4v acc[4] = {{0.f, 0.f, 0.f, 0.f}, {0.f, 0.f, 0.f, 0.f},
                  {0.f, 0.f, 0.f, 0.f}, {0.f, 0.f, 0.f, 0.f}};
    for (int k0 = 0; k0 < DINNER; k0 += 64) {
        __syncthreads();
#pragma unroll
        for (int i = 0; i < 2; ++i) {
            int c = t + i * 256, row = c >> 3, ch = (c & 7) * 8;
            *(uint4*)&As[row * PAD + ch] = *(const uint4*)&A[(size_t)(bm + row) * DINNER + k0 + ch];
            *(uint4*)&Bs[row * PAD + ch] = *(const uint4*)&Bt[(size_t)(bn + row) * DINNER + k0 + ch];
        }
        __syncthreads();
#pragma unroll
        for (int kk = 0; kk < 64; kk += 32) {
            s8v a = *(const s8v*)&As[(w * 16 + m) * PAD + kk + q * 8];
#pragma unroll
            for (int ct = 0; ct < 4; ++ct) {
                s8v b = *(const s8v*)&Bs[(ct * 16 + m) * PAD + kk + q * 8];
                acc[ct] = MFMA(a, b, acc[ct]);
            }
        }
    }
#pragma unroll
    for (int ct = 0; ct < 4; ++ct)
#pragma unroll
        for (int r = 0; r < 4; ++r)
            C[(size_t)(bm + w * 16 + q * 4 + r) * DIM + bn + ct * 16 + m] = acc[ct][r];
}

extern "C" void kernel_launch(void* const* d_in, const int* in_sizes, int n_in,
                              void* d_out, int out_size, void* d_ws, size_t ws_size,
                              hipStream_t stream) {
    const float* x     = (const float*)d_in[0];
    const float* gamma = (const float*)d_in[1];
    const float* w_qkv = (const float*)d_in[2];
    const float* w_out = (const float*)d_in[3];
    float* out = (float*)d_out;

    // normed hi/lo live in d_out (2 * 4096*1024 * 2B == 4096*1024 * 4B, exact fit;
    // fully consumed by gemm_qkv before attention partials overwrite d_out)
    u16* nh = (u16*)d_out;
    u16* nl = nh + (size_t)SEQ * DIM;

    u16* p = (u16*)d_ws;
    u16* wqt_h = p; p += (size_t)QKVW * DIM;
    u16* wqt_l = p; p += (size_t)QKVW * DIM;
    u16* wot   = p; p += (size_t)DIM * DINNER;
    u16* qh = p; p += (size_t)SEQ * DINNER;
    u16* ql = p; p += (size_t)SEQ * DINNER;
    u16* kh = p; p += (size_t)SEQ * DINNER;
    u16* kl = p; p += (size_t)SEQ * DINNER;
    u16* vt = p; p += (size_t)DINNER * SEQ;
    u16* atto = p; p += (size_t)SEQ * DINNER;

    // split-KV extra buffers: chunks 2,3 (fp32) + (m,l); chunks 0,1 reuse d_out
    const size_t po_elems = (size_t)HEADS * 64 * 64 * 64;  // 2,097,152 floats / chunk
    float* po2 = (float*)p;
    float* po3 = po2 + po_elems;
    float* ml  = po3 + po_elems;
    const size_t need = (size_t)((char*)(ml + (size_t)HEADS * 64 * 4 * 128) - (char*)d_ws);
    const bool split = ws_size >= need;   // 48 MiB total

    transpose_split<<<dim3(QKVW / 64, DIM / 64), 256, 0, stream>>>(w_qkv, wqt_h, wqt_l,
                                                                   DIM, QKVW, 1);
    transpose_split<<<dim3(DIM / 64, DINNER / 64), 256, 0, stream>>>(w_out, wot, nullptr,
                                                                     DINNER, DIM, 0);
    rmsnorm_split<<<SEQ, 256, 0, stream>>>(x, gamma, nh, nl);
    gemm_qkv_split<<<dim3(QKVW / 64, SEQ / 64), 256, 0, stream>>>(nh, nl, wqt_h, wqt_l,
                                                                  qh, ql, kh, kl, vt);
    if (split) {
        float* po0 = (float*)d_out;          // d_out free between gemm_qkv and gemm_out
        float* po1 = po0 + po_elems;
        attn_chunk<<<dim3(256, HEADS), 256, 0, stream>>>(qh, ql, kh, kl, vt,
                                                         po0, po1, po2, po3, ml);
        attn_merge<<<dim3(SEQ / 64, HEADS), 256, 0, stream>>>(po0, po1, po2, po3, ml, atto);
    } else {
        attn_mfma<<<dim3(SEQ / 64, HEADS), 256, 0, stream>>>(qh, ql, kh, kl, vt, atto);
    }
    gemm_out_bf16<<<dim3(DIM / 64, SEQ / 64), 256, 0, stream>>>(atto, wot, out);
}

// Round 2
// 321.294 us; speedup vs baseline: 1.2797x; 1.2797x over previous
//
#include <hip/hip_runtime.h>
#include <math.h>

#define SEQ 4096
#define DIM 1024
#define HEADS 8
#define DINNER 512
#define QKVW 1536
#define PAD 80   // LDS row stride in bf16 elems: 160B = 10 x 16B granules, balanced banks
#define CHUNK 16 // K-tiles (of 64) per split-KV chunk

typedef unsigned short u16;
typedef __attribute__((ext_vector_type(8))) short s8v;   // 8 bf16 (4 VGPRs)
typedef __attribute__((ext_vector_type(4))) float f4v;   // 4 fp32 acc
#define MFMA(a, b, c) __builtin_amdgcn_mfma_f32_16x16x32_bf16(a, b, c, 0, 0, 0)

__device__ __forceinline__ u16 f2bf(float f) {
    unsigned u = __float_as_uint(f);
    u += 0x7fff + ((u >> 16) & 1);   // RNE
    return (u16)(u >> 16);
}
__device__ __forceinline__ float bf2f(u16 b) { return __uint_as_float(((unsigned)b) << 16); }

// ---------- RMSNorm -> split bf16 (hi, lo) ----------
__global__ __launch_bounds__(256) void rmsnorm_split(const float* __restrict__ x,
                                                     const float* __restrict__ gamma,
                                                     u16* __restrict__ hi,
                                                     u16* __restrict__ lo) {
    __shared__ float red[4];
    const int row = blockIdx.x, t = threadIdx.x;
    const float* xr = x + (size_t)row * DIM;
    float v[4];
    float ss = 0.f;
#pragma unroll
    for (int i = 0; i < 4; ++i) { v[i] = xr[t + i * 256]; ss += v[i] * v[i]; }
#pragma unroll
    for (int off = 32; off >= 1; off >>= 1) ss += __shfl_xor(ss, off, 64);
    if ((t & 63) == 0) red[t >> 6] = ss;
    __syncthreads();
    float scale = 32.0f / fmaxf(sqrtf(red[0] + red[1] + red[2] + red[3]), 1e-12f);
#pragma unroll
    for (int i = 0; i < 4; ++i) {
        int c = t + i * 256;
        float y = v[i] * scale * gamma[c];
        u16 h = f2bf(y);
        hi[(size_t)row * DIM + c] = h;
        lo[(size_t)row * DIM + c] = f2bf(y - bf2f(h));
    }
}

// ---------- transpose fp32 [R][C] -> bf16 hi/lo [C][R] ----------
__global__ __launch_bounds__(256) void transpose_split(const float* __restrict__ in,
                                                       u16* __restrict__ hi,
                                                       u16* __restrict__ lo,
                                                       int R, int C, int want_lo) {
    __shared__ float tile[64][65];
    const int c0 = blockIdx.x * 64, r0 = blockIdx.y * 64;
    const int t = threadIdx.x, col = t & 63, rb = t >> 6;
#pragma unroll
    for (int j = 0; j < 16; ++j)
        tile[rb + j * 4][col] = in[(size_t)(r0 + rb + j * 4) * C + c0 + col];
    __syncthreads();
#pragma unroll
    for (int j = 0; j < 16; ++j) {
        int cc = rb + j * 4;
        float v = tile[col][cc];
        size_t oi = (size_t)(c0 + cc) * R + r0 + col;
        u16 h = f2bf(v);
        hi[oi] = h;
        if (want_lo) lo[oi] = f2bf(v - bf2f(h));
    }
}

// ---------- QKV GEMM, split-bf16 (3 MFMAs), fused split/scale epilogue ----------
__global__ __launch_bounds__(256) void gemm_qkv_split(
    const u16* __restrict__ Ah, const u16* __restrict__ Al,
    const u16* __restrict__ Bh, const u16* __restrict__ Bl,
    u16* __restrict__ qh, u16* __restrict__ ql,
    u16* __restrict__ kh, u16* __restrict__ kl, u16* __restrict__ vtp) {
    __shared__ u16 Ash[64 * PAD], Asl[64 * PAD], Bsh[64 * PAD], Bsl[64 * PAD];
    const int t = threadIdx.x;
    const int bn = blockIdx.x * 64, bm = blockIdx.y * 64;
    const int w = t >> 6, lane = t & 63, m = lane & 15, q = lane >> 4;
    f4v acc[4] = {{0.f, 0.f, 0.f, 0.f}, {0.f, 0.f, 0.f, 0.f},
                  {0.f, 0.f, 0.f, 0.f}, {0.f, 0.f, 0.f, 0.f}};
    for (int k0 = 0; k0 < DIM; k0 += 64) {
        __syncthreads();
#pragma unroll
        for (int i = 0; i < 2; ++i) {
            int c = t + i * 256, row = c >> 3, ch = (c & 7) * 8;
            *(uint4*)&Ash[row * PAD + ch] = *(const uint4*)&Ah[(size_t)(bm + row) * DIM + k0 + ch];
            *(uint4*)&Asl[row * PAD + ch] = *(const uint4*)&Al[(size_t)(bm + row) * DIM + k0 + ch];
            *(uint4*)&Bsh[row * PAD + ch] = *(const uint4*)&Bh[(size_t)(bn + row) * DIM + k0 + ch];
            *(uint4*)&Bsl[row * PAD + ch] = *(const uint4*)&Bl[(size_t)(bn + row) * DIM + k0 + ch];
        }
        __syncthreads();
#pragma unroll
        for (int kk = 0; kk < 64; kk += 32) {
            s8v ah = *(const s8v*)&Ash[(w * 16 + m) * PAD + kk + q * 8];
            s8v al = *(const s8v*)&Asl[(w * 16 + m) * PAD + kk + q * 8];
#pragma unroll
            for (int ct = 0; ct < 4; ++ct) {
                s8v bh = *(const s8v*)&Bsh[(ct * 16 + m) * PAD + kk + q * 8];
                s8v bl = *(const s8v*)&Bsl[(ct * 16 + m) * PAD + kk + q * 8];
                acc[ct] = MFMA(ah, bh, acc[ct]);
                acc[ct] = MFMA(al, bh, acc[ct]);
                acc[ct] = MFMA(ah, bl, acc[ct]);
            }
        }
    }
    const int region = bn >> 9;   // uniform per block
#pragma unroll
    for (int ct = 0; ct < 4; ++ct) {
#pragma unroll
        for (int r = 0; r < 4; ++r) {
            int gr = bm + w * 16 + q * 4 + r;
            int gc = bn + ct * 16 + m;
            float v = acc[ct][r];
            if (region == 0) {
                v *= 8.0f;   // q * sqrt(d), faithful to reference
                u16 h = f2bf(v);
                qh[(size_t)gr * DINNER + gc] = h;
                ql[(size_t)gr * DINNER + gc] = f2bf(v - bf2f(h));
            } else if (region == 1) {
                u16 h = f2bf(v);
                kh[(size_t)gr * DINNER + (gc - 512)] = h;
                kl[(size_t)gr * DINNER + (gc - 512)] = f2bf(v - bf2f(h));
            } else {
                vtp[(size_t)(gc - 1024) * SEQ + gr] = f2bf(v);
            }
        }
    }
}

// ---------- split-KV flash attention chunk kernel ----------
// blockIdx.x encodes (qt descending, chunk c in 0..3); qt handles K-tiles [c*16, min(qt, c*16+15)].
// Q hi/lo fragments live in registers (each wave reads only its own 16 rows).
// Staging is transient (load -> immediate LDS write, short live ranges): the R1 register
// prefetch spilled to scratch (WRITE_SIZE 296 MB, 15.8 us/iter) -- do NOT hold staging
// registers across the compute phase without VGPR budget.
// Writes RAW partial o (fp32), plus per-row running (m, l) for the merge pass.
__global__ __launch_bounds__(256) void attn_chunk(
    const u16* __restrict__ qhp, const u16* __restrict__ qlp,
    const u16* __restrict__ kh, const u16* __restrict__ kl,
    const u16* __restrict__ vt,
    float* __restrict__ po0, float* __restrict__ po1,
    float* __restrict__ po2, float* __restrict__ po3,
    float* __restrict__ ml) {
    __shared__ u16 KP[64 * PAD], Kl[64 * PAD], Vt[64 * PAD];
    const int t = threadIdx.x;
    const int bx = blockIdx.x;
    const int qt = 63 - (bx >> 2), c = bx & 3, h = blockIdx.y;
    if (c * CHUNK > qt) return;
    const int kt0 = c * CHUNK;
    const int kt1 = (qt < kt0 + CHUNK - 1) ? qt : (kt0 + CHUNK - 1);
    const int w = t >> 6, lane = t & 63, m = lane & 15, q = lane >> 4;

    // Q fragments in registers: row = qt*64 + w*16 + m, cols q*8 + {0..7} and 32 + q*8 + {0..7}
    const size_t qrow = (size_t)(qt * 64 + w * 16 + m) * DINNER + h * 64;
    const s8v qf_h0 = *(const s8v*)&qhp[qrow + q * 8];
    const s8v qf_h1 = *(const s8v*)&qhp[qrow + 32 + q * 8];
    const s8v qf_l0 = *(const s8v*)&qlp[qrow + q * 8];
    const s8v qf_l1 = *(const s8v*)&qlp[qrow + 32 + q * 8];

    f4v o[4] = {{0.f, 0.f, 0.f, 0.f}, {0.f, 0.f, 0.f, 0.f},
                {0.f, 0.f, 0.f, 0.f}, {0.f, 0.f, 0.f, 0.f}};
    float mi[4] = {-1e30f, -1e30f, -1e30f, -1e30f};
    float li[4] = {0.f, 0.f, 0.f, 0.f};

    for (int kt = kt0; kt <= kt1; ++kt) {
        __syncthreads();   // prior iteration's P/Vt consumers done
#pragma unroll
        for (int i = 0; i < 2; ++i) {
            int c2 = t + i * 256, row = c2 >> 3, ch = (c2 & 7) * 8;
            *(uint4*)&KP[row * PAD + ch] =
                *(const uint4*)&kh[(size_t)(kt * 64 + row) * DINNER + h * 64 + ch];
            *(uint4*)&Kl[row * PAD + ch] =
                *(const uint4*)&kl[(size_t)(kt * 64 + row) * DINNER + h * 64 + ch];
            *(uint4*)&Vt[row * PAD + ch] =
                *(const uint4*)&vt[(size_t)(h * 64 + row) * SEQ + kt * 64 + ch];
        }
        __syncthreads();

        // S strip (16 rows x 64 cols) per wave, split QK^T: 3 MFMAs per 16x16x32
        f4v s[4] = {{0.f, 0.f, 0.f, 0.f}, {0.f, 0.f, 0.f, 0.f},
                    {0.f, 0.f, 0.f, 0.f}, {0.f, 0.f, 0.f, 0.f}};
#pragma unroll
        for (int ct = 0; ct < 4; ++ct) {
            s8v bh0 = *(const s8v*)&KP[(ct * 16 + m) * PAD + q * 8];
            s8v bl0 = *(const s8v*)&Kl[(ct * 16 + m) * PAD + q * 8];
            s[ct] = MFMA(qf_h0, bh0, s[ct]);
            s[ct] = MFMA(qf_l0, bh0, s[ct]);
            s[ct] = MFMA(qf_h0, bl0, s[ct]);
            s8v bh1 = *(const s8v*)&KP[(ct * 16 + m) * PAD + 32 + q * 8];
            s8v bl1 = *(const s8v*)&Kl[(ct * 16 + m) * PAD + 32 + q * 8];
            s[ct] = MFMA(qf_h1, bh1, s[ct]);
            s[ct] = MFMA(qf_l1, bh1, s[ct]);
            s[ct] = MFMA(qf_h1, bl1, s[ct]);
        }
        if (kt == qt) {   // causal: mask col > row (tile-local, same tile offset)
#pragma unroll
            for (int ct = 0; ct < 4; ++ct)
#pragma unroll
                for (int r = 0; r < 4; ++r)
                    if (ct * 16 + m > w * 16 + q * 4 + r) s[ct][r] = -1e30f;
        }

        // online softmax: row = w*16 + q*4 + r lives on the 16-lane group (lane>>4)==q
        float alpha[4];
#pragma unroll
        for (int r = 0; r < 4; ++r) {
            float rm = fmaxf(fmaxf(s[0][r], s[1][r]), fmaxf(s[2][r], s[3][r]));
#pragma unroll
            for (int off = 8; off >= 1; off >>= 1) rm = fmaxf(rm, __shfl_xor(rm, off, 64));
            float mn = fmaxf(mi[r], rm);
            alpha[r] = __expf(mi[r] - mn);
            mi[r] = mn;
            float rs = 0.f;
#pragma unroll
            for (int ct = 0; ct < 4; ++ct) {
                s[ct][r] = __expf(s[ct][r] - mn);
                rs += s[ct][r];
            }
#pragma unroll
            for (int off = 8; off >= 1; off >>= 1) rs += __shfl_xor(rs, off, 64);
            li[r] = li[r] * alpha[r] + rs;
        }

        __syncthreads();   // all waves done reading KP as K-hi before P overwrite
#pragma unroll
        for (int ct = 0; ct < 4; ++ct)
#pragma unroll
            for (int r = 0; r < 4; ++r) {
                KP[(w * 16 + q * 4 + r) * PAD + ct * 16 + m] = f2bf(s[ct][r]);
                o[ct][r] *= alpha[r];
            }
        // PV: each wave reads only its own P rows (w*16..w*16+15) -> no barrier needed
#pragma unroll
        for (int kk = 0; kk < 64; kk += 32) {
            s8v ap = *(const s8v*)&KP[(w * 16 + m) * PAD + kk + q * 8];
#pragma unroll
            for (int ct = 0; ct < 4; ++ct) {
                s8v bv = *(const s8v*)&Vt[(ct * 16 + m) * PAD + kk + q * 8];
                o[ct] = MFMA(ap, bv, o[ct]);
            }
        }
    }

    // epilogue: raw partial o (fp32) + per-row (m, l)
    float* po = (c == 0) ? po0 : (c == 1) ? po1 : (c == 2) ? po2 : po3;
    const size_t pbase = (size_t)(h * 64 + qt) * 64 * 64;
#pragma unroll
    for (int ct = 0; ct < 4; ++ct)
#pragma unroll
        for (int r = 0; r < 4; ++r)
            po[pbase + (size_t)(w * 16 + q * 4 + r) * 64 + ct * 16 + m] = o[ct][r];
    if (m == 0) {
#pragma unroll
        for (int r = 0; r < 4; ++r) {
            int row = w * 16 + q * 4 + r;
            ml[((size_t)(h * 64 + qt) * 4 + c) * 128 + row] = mi[r];
            ml[((size_t)(h * 64 + qt) * 4 + c) * 128 + 64 + row] = li[r];
        }
    }
}

// ---------- merge split-KV partials -> atto bf16 ----------
__global__ __launch_bounds__(256) void attn_merge(
    const float* __restrict__ po0, const float* __restrict__ po1,
    const float* __restrict__ po2, const float* __restrict__ po3,
    const float* __restrict__ ml, u16* __restrict__ atto) {
    const int qt = blockIdx.x, h = blockIdx.y;
    const int nc = qt / CHUNK + 1;
    const int t = threadIdx.x, col = t & 63, rg = t >> 6;
    const size_t mlb = (size_t)(h * 64 + qt) * 4;
    const size_t pb = (size_t)(h * 64 + qt) * 64;
    for (int j = 0; j < 16; ++j) {
        int row = rg * 16 + j;
        float mv[4], lv[4];
        float M = -1e30f;
#pragma unroll
        for (int cc = 0; cc < 4; ++cc)
            if (cc < nc) {
                mv[cc] = ml[(mlb + cc) * 128 + row];
                lv[cc] = ml[(mlb + cc) * 128 + 64 + row];
                M = fmaxf(M, mv[cc]);
            }
        const size_t oidx = (pb + row) * 64 + col;
        float acc = 0.f, den = 0.f;
        { float wg = __expf(mv[0] - M); den += lv[0] * wg; acc += wg * po0[oidx]; }
        if (1 < nc) { float wg = __expf(mv[1] - M); den += lv[1] * wg; acc += wg * po1[oidx]; }
        if (2 < nc) { float wg = __expf(mv[2] - M); den += lv[2] * wg; acc += wg * po2[oidx]; }
        if (3 < nc) { float wg = __expf(mv[3] - M); den += lv[3] * wg; acc += wg * po3[oidx]; }
        atto[(size_t)(qt * 64 + row) * DINNER + h * 64 + col] = f2bf(acc / den);
    }
}

// ---------- fallback: original fused flash attention (used if workspace too small) ----------
__global__ __launch_bounds__(256) void attn_mfma(
    const u16* __restrict__ qh, const u16* __restrict__ ql,
    const u16* __restrict__ kh, const u16* __restrict__ kl,
    const u16* __restrict__ vt, u16* __restrict__ atto) {
    __shared__ u16 Qh[64 * PAD], Ql[64 * PAD], KP[64 * PAD], Kl[64 * PAD], Vt[64 * PAD];
    const int t = threadIdx.x;
    const int qt = blockIdx.x, h = blockIdx.y;
    const int w = t >> 6, lane = t & 63, m = lane & 15, q = lane >> 4;

#pragma unroll
    for (int i = 0; i < 2; ++i) {
        int c = t + i * 256, row = c >> 3, ch = (c & 7) * 8;
        *(uint4*)&Qh[row * PAD + ch] =
            *(const uint4*)&qh[(size_t)(qt * 64 + row) * DINNER + h * 64 + ch];
        *(uint4*)&Ql[row * PAD + ch] =
            *(const uint4*)&ql[(size_t)(qt * 64 + row) * DINNER + h * 64 + ch];
    }

    f4v o[4] = {{0.f, 0.f, 0.f, 0.f}, {0.f, 0.f, 0.f, 0.f},
                {0.f, 0.f, 0.f, 0.f}, {0.f, 0.f, 0.f, 0.f}};
    float mi[4] = {-1e30f, -1e30f, -1e30f, -1e30f};
    float li[4] = {0.f, 0.f, 0.f, 0.f};

    for (int kt = 0; kt <= qt; ++kt) {
        __syncthreads();
#pragma unroll
        for (int i = 0; i < 2; ++i) {
            int c = t + i * 256, row = c >> 3, ch = (c & 7) * 8;
            *(uint4*)&KP[row * PAD + ch] =
                *(const uint4*)&kh[(size_t)(kt * 64 + row) * DINNER + h * 64 + ch];
            *(uint4*)&Kl[row * PAD + ch] =
                *(const uint4*)&kl[(size_t)(kt * 64 + row) * DINNER + h * 64 + ch];
            *(uint4*)&Vt[row * PAD + ch] =
                *(const uint4*)&vt[(size_t)(h * 64 + row) * SEQ + kt * 64 + ch];
        }
        __syncthreads();

        f4v s[4] = {{0.f, 0.f, 0.f, 0.f}, {0.f, 0.f, 0.f, 0.f},
                    {0.f, 0.f, 0.f, 0.f}, {0.f, 0.f, 0.f, 0.f}};
#pragma unroll
        for (int kk = 0; kk < 64; kk += 32) {
            s8v ah = *(const s8v*)&Qh[(w * 16 + m) * PAD + kk + q * 8];
            s8v al = *(const s8v*)&Ql[(w * 16 + m) * PAD + kk + q * 8];
#pragma unroll
            for (int ct = 0; ct < 4; ++ct) {
                s8v bh = *(const s8v*)&KP[(ct * 16 + m) * PAD + kk + q * 8];
                s8v bl = *(const s8v*)&Kl[(ct * 16 + m) * PAD + kk + q * 8];
                s[ct] = MFMA(ah, bh, s[ct]);
                s[ct] = MFMA(al, bh, s[ct]);
                s[ct] = MFMA(ah, bl, s[ct]);
            }
        }
        if (kt == qt) {
#pragma unroll
            for (int ct = 0; ct < 4; ++ct)
#pragma unroll
                for (int r = 0; r < 4; ++r)
                    if (ct * 16 + m > w * 16 + q * 4 + r) s[ct][r] = -1e30f;
        }

        float alpha[4];
#pragma unroll
        for (int r = 0; r < 4; ++r) {
            float rm = fmaxf(fmaxf(s[0][r], s[1][r]), fmaxf(s[2][r], s[3][r]));
#pragma unroll
            for (int off = 8; off >= 1; off >>= 1) rm = fmaxf(rm, __shfl_xor(rm, off, 64));
            float mn = fmaxf(mi[r], rm);
            alpha[r] = __expf(mi[r] - mn);
            mi[r] = mn;
            float rs = 0.f;
#pragma unroll
            for (int ct = 0; ct < 4; ++ct) {
                s[ct][r] = __expf(s[ct][r] - mn);
                rs += s[ct][r];
            }
#pragma unroll
            for (int off = 8; off >= 1; off >>= 1) rs += __shfl_xor(rs, off, 64);
            li[r] = li[r] * alpha[r] + rs;
        }

        __syncthreads();
#pragma unroll
        for (int ct = 0; ct < 4; ++ct)
#pragma unroll
            for (int r = 0; r < 4; ++r) {
                KP[(w * 16 + q * 4 + r) * PAD + ct * 16 + m] = f2bf(s[ct][r]);
                o[ct][r] *= alpha[r];
            }
#pragma unroll
        for (int kk = 0; kk < 64; kk += 32) {
            s8v ap = *(const s8v*)&KP[(w * 16 + m) * PAD + kk + q * 8];
#pragma unroll
            for (int ct = 0; ct < 4; ++ct) {
                s8v bv = *(const s8v*)&Vt[(ct * 16 + m) * PAD + kk + q * 8];
                o[ct] = MFMA(ap, bv, o[ct]);
            }
        }
    }

#pragma unroll
    for (int r = 0; r < 4; ++r) {
        float inv = 1.0f / li[r];
#pragma unroll
        for (int ct = 0; ct < 4; ++ct)
            atto[(size_t)(qt * 64 + w * 16 + q * 4 + r) * DINNER + h * 64 + ct * 16 + m] =
                f2bf(o[ct][r] * inv);
    }
}

// ---------- out projection: atto bf16 [4096][512] @ w_out^T bf16 [1024][512] -> fp32 ----------
__global__ __launch_bounds__(256) void gemm_out_bf16(const u16* __restrict__ A,
                                                     const u16* __restrict__ Bt,
                                                     float* __restrict__ C) {
    __shared__ u16 As[64 * PAD], Bs[64 * PAD];
    const int t = threadIdx.x;
    const int bn = blockIdx.x * 64, bm = blockIdx.y * 64;
    const int w = t >> 6, lane = t & 63, m = lane & 15, q = lane >> 4;
    f4v acc[4] = {{0.f, 0.f, 0.f, 0.f}, {0.f, 0.f, 0.f, 0.f},
                  {0.f, 0.f, 0.f, 0.f}, {0.f, 0.f, 0.f, 0.f}};
    for (int k0 = 0; k0 < DINNER; k0 += 64) {
        __syncthreads();
#pragma unroll
        for (int i = 0; i < 2; ++i) {
            int c = t + i * 256, row = c >> 3, ch = (c & 7) * 8;
            *(uint4*)&As[row * PAD + ch] = *(const uint4*)&A[(size_t)(bm + row) * DINNER + k0 + ch];
            *(uint4*)&Bs[row * PAD + ch] = *(const uint4*)&Bt[(size_t)(bn + row) * DINNER + k0 + ch];
        }
        __syncthreads();
#pragma unroll
        for (int kk = 0; kk < 64; kk += 32) {
            s8v a = *(const s8v*)&As[(w * 16 + m) * PAD + kk + q * 8];
#pragma unroll
            for (int ct = 0; ct < 4; ++ct) {
                s8v b = *(const s8v*)&Bs[(ct * 16 + m) * PAD + kk + q * 8];
                acc[ct] = MFMA(a, b, acc[ct]);
            }
        }
    }
#pragma unroll
    for (int ct = 0; ct < 4; ++ct)
#pragma unroll
        for (int r = 0; r < 4; ++r)
            C[(size_t)(bm + w * 16 + q * 4 + r) * DIM + bn + ct * 16 + m] = acc[ct][r];
}

extern "C" void kernel_launch(void* const* d_in, const int* in_sizes, int n_in,
                              void* d_out, int out_size, void* d_ws, size_t ws_size,
                              hipStream_t stream) {
    const float* x     = (const float*)d_in[0];
    const float* gamma = (const float*)d_in[1];
    const float* w_qkv = (const float*)d_in[2];
    const float* w_out = (const float*)d_in[3];
    float* out = (float*)d_out;

    // normed hi/lo live in d_out (2 * 4096*1024 * 2B == 4096*1024 * 4B, exact fit;
    // fully consumed by gemm_qkv before attention partials overwrite d_out)
    u16* nh = (u16*)d_out;
    u16* nl = nh + (size_t)SEQ * DIM;

    u16* p = (u16*)d_ws;
    u16* wqt_h = p; p += (size_t)QKVW * DIM;
    u16* wqt_l = p; p += (size_t)QKVW * DIM;
    u16* wot   = p; p += (size_t)DIM * DINNER;
    u16* qh = p; p += (size_t)SEQ * DINNER;
    u16* ql = p; p += (size_t)SEQ * DINNER;
    u16* kh = p; p += (size_t)SEQ * DINNER;
    u16* kl = p; p += (size_t)SEQ * DINNER;
    u16* vt = p; p += (size_t)DINNER * SEQ;
    u16* atto = p; p += (size_t)SEQ * DINNER;

    // split-KV extra buffers: chunks 2,3 (fp32) + (m,l); chunks 0,1 reuse d_out
    const size_t po_elems = (size_t)HEADS * 64 * 64 * 64;  // 2,097,152 floats / chunk
    float* po2 = (float*)p;
    float* po3 = po2 + po_elems;
    float* ml  = po3 + po_elems;
    const size_t need = (size_t)((char*)(ml + (size_t)HEADS * 64 * 4 * 128) - (char*)d_ws);
    const bool split = ws_size >= need;   // 48 MiB total

    transpose_split<<<dim3(QKVW / 64, DIM / 64), 256, 0, stream>>>(w_qkv, wqt_h, wqt_l,
                                                                   DIM, QKVW, 1);
    transpose_split<<<dim3(DIM / 64, DINNER / 64), 256, 0, stream>>>(w_out, wot, nullptr,
                                                                     DINNER, DIM, 0);
    rmsnorm_split<<<SEQ, 256, 0, stream>>>(x, gamma, nh, nl);
    gemm_qkv_split<<<dim3(QKVW / 64, SEQ / 64), 256, 0, stream>>>(nh, nl, wqt_h, wqt_l,
                                                                  qh, ql, kh, kl, vt);
    if (split) {
        float* po0 = (float*)d_out;          // d_out free between gemm_qkv and gemm_out
        float* po1 = po0 + po_elems;
        attn_chunk<<<dim3(256, HEADS), 256, 0, stream>>>(qh, ql, kh, kl, vt,
                                                         po0, po1, po2, po3, ml);
        attn_merge<<<dim3(SEQ / 64, HEADS), 256, 0, stream>>>(po0, po1, po2, po3, ml, atto);
    } else {
        attn_mfma<<<dim3(SEQ / 64, HEADS), 256, 0, stream>>>(qh, ql, kh, kl, vt, atto);
    }
    gemm_out_bf16<<<dim3(DIM / 64, SEQ / 64), 256, 0, stream>>>(atto, wot, out);
}